// Round 3
// baseline (67.144 us; speedup 1.0000x reference)
//
#include <hip/hip_runtime.h>
#include <stdint.h>

#define N_OUT    4096
#define N_IN     4096
#define TOKENS   256
#define N_SPARSE 8388608
#define SPLITK   16
#define KCHUNK   (N_IN / SPLITK)   // 256
#define BM       128
#define BN       128
#define BK       64

typedef __attribute__((ext_vector_type(8))) short bf16x8;
typedef __attribute__((ext_vector_type(8))) unsigned short u16x8;
typedef __attribute__((ext_vector_type(4))) float f32x4;

__device__ __forceinline__ unsigned short f2bf(float f) {
    union { float f; unsigned u; } v; v.f = f;
    unsigned r = v.u + 0x7fffu + ((v.u >> 16) & 1u);   // RNE
    return (unsigned short)(r >> 16);
}

__device__ __forceinline__ void gload_lds16(const void* g, void* l) {
    __builtin_amdgcn_global_load_lds(
        (const __attribute__((address_space(1))) void*)g,
        (__attribute__((address_space(3))) void*)l, 16, 0, 0);
}

// ---- kernel 1: x (fp32) -> xb (bf16) -------------------------------------
__global__ void convert_x(const float* __restrict__ x, unsigned short* __restrict__ xb) {
    int i = (blockIdx.x * 256 + threadIdx.x) * 4;
    const float4 v = *(const float4*)(x + i);
    ushort4 o;
    o.x = f2bf(v.x); o.y = f2bf(v.y); o.z = f2bf(v.z); o.w = f2bf(v.w);
    *(ushort4*)(xb + i) = o;
}

// ---- kernel 2a: row_ptr[r] = lower_bound(idx, r*N_IN), r in [0, N_OUT] ----
__global__ void row_ptr_k(const int* __restrict__ idx, int* __restrict__ rp) {
    const int r = blockIdx.x * 256 + threadIdx.x;
    if (r > N_OUT) return;
    const int target = r << 12;            // r * N_IN
    int lo = 0, hi = N_SPARSE;
    while (lo < hi) { int m = (lo + hi) >> 1; if (idx[m] < target) lo = m + 1; else hi = m; }
    rp[r] = lo;
}

// ---- kernel 2b: build dense bf16 W row-by-row via LDS staging -------------
// One block per row: zero 8KB LDS row (16B stores), scatter nonzeros into LDS
// (2B LDS writes), vector-copy LDS -> global (16B stores). Every W element
// written exactly once per launch; no memset pass, no scalar global stores.
__global__ __launch_bounds__(256) void build_w(const int* __restrict__ idx,
                                               const float* __restrict__ vals,
                                               const int* __restrict__ rp,
                                               unsigned short* __restrict__ wb) {
    __shared__ unsigned short row[N_IN];   // 8KB
    const int r = blockIdx.x;
    const int t = threadIdx.x;
    const int base = r << 12;

    const u16x8 z = (u16x8)0;
    *(u16x8*)&row[t * 16]     = z;
    *(u16x8*)&row[t * 16 + 8] = z;

    const int start = rp[r];
    const int end   = rp[r + 1];
    __syncthreads();

    for (int j = start + t; j < end; j += 256)
        row[idx[j] - base] = f2bf(vals[j]);
    __syncthreads();

    unsigned short* wo = wb + (size_t)base + t * 16;
    *(u16x8*)wo       = *(const u16x8*)&row[t * 16];
    *(u16x8*)(wo + 8) = *(const u16x8*)&row[t * 16 + 8];
}

// ---- kernel 3: bf16 MFMA GEMM, A (M x K) rm, B (N x K) rm, split-K --------
// LDS tiles hold XOR-swizzled rows: 16B slot s of row r stores global slot
// s ^ (r & 7) (pre-swizzled global source, linear global_load_lds dest).
// ds_read_b128 applies the same XOR -> per-bank-quad load perfectly balanced.
__global__ __launch_bounds__(256) void gemm_bt_splitk(
        const unsigned short* __restrict__ xb,   // 256 x 4096 bf16
        const unsigned short* __restrict__ wb,   // 4096 x 4096 bf16
        float* __restrict__ part)                // SPLITK x 256 x 4096 f32
{
    __shared__ short As[BM * BK];   // 16KB
    __shared__ short Bs[BN * BK];   // 16KB

    const int tid = threadIdx.x;
    const int l   = tid & 63;
    const int w   = tid >> 6;
    const int bn  = blockIdx.x;
    const int bm  = blockIdx.y;
    const int bz  = blockIdx.z;

    const size_t k0 = (size_t)bz * KCHUNK;
    const unsigned short* ag = xb + (size_t)(bm * BM) * N_IN + k0;
    const unsigned short* bg = wb + (size_t)(bn * BN) * N_IN + k0;

    // staging: round ro, wave w covers rows [ro*32 + w*8, +8); lane l ->
    // row offset l>>3, 16B slot l&7, global slot swizzled by row&7 (= l>>3)
    const int srow = l >> 3;
    const int sgq  = (l & 7) ^ srow;

    const int mbase = (w >> 1) * 64;
    const int nbase = (w & 1) * 64;
    const int lr = l & 15;
    const int kg = (l >> 4) * 8;

    f32x4 acc[4][4] = {};

    for (int kt = 0; kt < KCHUNK; kt += BK) {
        #pragma unroll
        for (int ro = 0; ro < 4; ++ro) {
            const int rbase = ro * 32 + w * 8;
            gload_lds16(ag + (size_t)(rbase + srow) * N_IN + kt + sgq * 8, &As[rbase * BK]);
            gload_lds16(bg + (size_t)(rbase + srow) * N_IN + kt + sgq * 8, &Bs[rbase * BK]);
        }
        __syncthreads();   // drains vmcnt(0): LDS tiles ready

        #pragma unroll
        for (int kk = 0; kk < 2; ++kk) {
            bf16x8 af[4], bfr[4];
            #pragma unroll
            for (int i = 0; i < 4; ++i) {
                const int row = mbase + i * 16 + lr;
                af[i] = *(const bf16x8*)&As[row * BK + ((kk * 32 + kg) ^ ((row & 7) * 8))];
            }
            #pragma unroll
            for (int i = 0; i < 4; ++i) {
                const int row = nbase + i * 16 + lr;
                bfr[i] = *(const bf16x8*)&Bs[row * BK + ((kk * 32 + kg) ^ ((row & 7) * 8))];
            }
            #pragma unroll
            for (int mi = 0; mi < 4; ++mi)
                #pragma unroll
                for (int ni = 0; ni < 4; ++ni)
                    acc[mi][ni] = __builtin_amdgcn_mfma_f32_16x16x32_bf16(
                                      af[mi], bfr[ni], acc[mi][ni], 0, 0, 0);
        }
        __syncthreads();
    }

    // epilogue: C/D layout col = lane&15, row = (lane>>4)*4 + reg
    float* po = part + (size_t)bz * (TOKENS * N_OUT)
                     + (size_t)(bm * BM + mbase) * N_OUT + bn * BN + nbase;
    const int rq = (l >> 4) * 4;
    #pragma unroll
    for (int mi = 0; mi < 4; ++mi)
        #pragma unroll
        for (int r = 0; r < 4; ++r) {
            const int row = mi * 16 + rq + r;
            #pragma unroll
            for (int ni = 0; ni < 4; ++ni)
                po[(size_t)row * N_OUT + ni * 16 + lr] = acc[mi][ni][r];
        }
}

// ---- kernel 4: sum split-K partials --------------------------------------
__global__ void reduce_k(const float* __restrict__ part, float* __restrict__ out) {
    int i = (blockIdx.x * 256 + threadIdx.x) * 4;
    float4 a = *(const float4*)(part + i);
    #pragma unroll
    for (int z = 1; z < SPLITK; ++z) {
        float4 b = *(const float4*)(part + (size_t)z * (TOKENS * N_OUT) + i);
        a.x += b.x; a.y += b.y; a.z += b.z; a.w += b.w;
    }
    *(float4*)(out + i) = a;
}

// ---- fallback (ws too small): per-output-row CSR, fp32 -------------------
__global__ void fallback_rowcsr(const float* __restrict__ x, const float* __restrict__ vals,
                                const int* __restrict__ idx, float* __restrict__ out) {
    const int o = blockIdx.x;
    const int t = threadIdx.x;
    __shared__ int   scol[256];
    __shared__ float sval[256];

    int lo = 0, hi = N_SPARSE;
    const int target = o * N_IN;
    while (lo < hi) { int m = (lo + hi) >> 1; if (idx[m] < target) lo = m + 1; else hi = m; }
    const int start = lo;
    hi = N_SPARSE;
    const int target2 = target + N_IN;
    while (lo < hi) { int m = (lo + hi) >> 1; if (idx[m] < target2) lo = m + 1; else hi = m; }
    const int end = lo;

    float acc = 0.f;
    const float* xr = x + (size_t)t * N_IN;
    for (int base = start; base < end; base += 256) {
        const int k = base + t;
        if (k < end) { scol[t] = idx[k] - target; sval[t] = vals[k]; }
        __syncthreads();
        const int cnt = min(256, end - base);
        for (int j = 0; j < cnt; ++j) acc += sval[j] * xr[scol[j]];
        __syncthreads();
    }
    out[(size_t)t * N_OUT + o] = acc;
}

extern "C" void kernel_launch(void* const* d_in, const int* in_sizes, int n_in,
                              void* d_out, int out_size, void* d_ws, size_t ws_size,
                              hipStream_t stream) {
    const float* x    = (const float*)d_in[0];
    const float* vals = (const float*)d_in[1];
    const int*   idx  = (const int*)d_in[2];
    float* out = (float*)d_out;

    const size_t wb_bytes   = (size_t)N_OUT * N_IN * 2;              // 32 MB
    const size_t xb_bytes   = (size_t)TOKENS * N_IN * 2;             // 2 MB
    const size_t part_bytes = (size_t)SPLITK * TOKENS * N_OUT * 4;   // 64 MB
    const size_t rp_bytes   = (size_t)(N_OUT + 1) * 4;
    const size_t need = wb_bytes + xb_bytes + part_bytes + rp_bytes; // ~98 MB

    if (ws_size >= need) {
        unsigned short* wb = (unsigned short*)d_ws;
        unsigned short* xb = (unsigned short*)((char*)d_ws + wb_bytes);
        float* part        = (float*)((char*)d_ws + wb_bytes + xb_bytes);
        int*   rp          = (int*)((char*)d_ws + wb_bytes + xb_bytes + part_bytes);

        convert_x<<<(TOKENS * N_IN) / 1024, 256, 0, stream>>>(x, xb);
        row_ptr_k<<<(N_OUT + 256) / 256, 256, 0, stream>>>(idx, rp);
        build_w<<<N_OUT, 256, 0, stream>>>(idx, vals, rp, wb);
        dim3 grid(N_OUT / BN, TOKENS / BM, SPLITK);
        gemm_bt_splitk<<<grid, 256, 0, stream>>>(xb, wb, part);
        reduce_k<<<(TOKENS * N_OUT) / 1024, 256, 0, stream>>>(part, out);
    } else {
        fallback_rowcsr<<<N_OUT, TOKENS, 0, stream>>>(x, vals, idx, out);
    }
}

// Round 4
// 56.089 us; speedup vs baseline: 1.1971x; 1.1971x over previous
//
#include <hip/hip_runtime.h>
#include <stdint.h>

#define N_OUT    4096
#define N_IN     4096
#define TOKENS   256
#define N_SPARSE 8388608
#define SPLITK   16
#define KCHUNK   (N_IN / SPLITK)   // 256
#define BN       64
#define BK       64
#define CPW      (SPLITK + 1)      // 17 col_ptr entries per row

typedef __attribute__((ext_vector_type(8))) short bf16x8;
typedef __attribute__((ext_vector_type(8))) unsigned short u16x8;
typedef __attribute__((ext_vector_type(4))) float f32x4;

__device__ __forceinline__ unsigned short f2bf(float f) {
    union { float f; unsigned u; } v; v.f = f;
    unsigned r = v.u + 0x7fffu + ((v.u >> 16) & 1u);   // RNE
    return (unsigned short)(r >> 16);
}

__device__ __forceinline__ float bf2f(unsigned short u) {
    union { unsigned u; float f; } v; v.u = ((unsigned)u) << 16;
    return v.f;
}

__device__ __forceinline__ void gload_lds16(const void* g, void* l) {
    __builtin_amdgcn_global_load_lds(
        (const __attribute__((address_space(1))) void*)g,
        (__attribute__((address_space(3))) void*)l, 16, 0, 0);
}

// ---- kernel 1: x (fp32) -> xb (bf16) -------------------------------------
__global__ void convert_x(const float* __restrict__ x, unsigned short* __restrict__ xb) {
    int i = (blockIdx.x * 256 + threadIdx.x) * 4;
    const float4 v = *(const float4*)(x + i);
    ushort4 o;
    o.x = f2bf(v.x); o.y = f2bf(v.y); o.z = f2bf(v.z); o.w = f2bf(v.w);
    *(ushort4*)(xb + i) = o;
}

// ---- kernel 2: cp[r][z] = lower_bound(idx, r*N_IN + z*KCHUNK) -------------
__global__ void col_ptr_k(const int* __restrict__ idx, int* __restrict__ cp) {
    const int e = blockIdx.x * 256 + threadIdx.x;
    if (e >= N_OUT * CPW) return;
    const int r = e / CPW;
    const int z = e - r * CPW;
    const int target = r * N_IN + z * KCHUNK;
    int lo = 0, hi = N_SPARSE;
    while (lo < hi) { int m = (lo + hi) >> 1; if (idx[m] < target) lo = m + 1; else hi = m; }
    cp[e] = lo;
}

// ---- kernel 3: fused sparse-scatter + MFMA GEMM, split-K ------------------
// Block (bn, bz): builds its 64x256 bf16 B-tile in LDS straight from
// (idx, vals) (XOR-swizzled: 16B slot s of row n holds global slot s^(n&7)),
// streams A (all 256 tokens) in BK=64 steps via global_load_lds, MFMA,
// writes bf16 partials. Dense W never materialized.
__global__ __launch_bounds__(512) void fused_gemm(
        const unsigned short* __restrict__ xb,   // 256 x 4096 bf16
        const int* __restrict__ idx,
        const float* __restrict__ vals,
        const int* __restrict__ cp,
        unsigned short* __restrict__ part)       // SPLITK x 256 x 4096 bf16
{
    __shared__ short As[TOKENS * BK];    // 32KB, swizzled rows of x-chunk
    __shared__ short Bs[BN * KCHUNK];    // 32KB, swizzled sparse tile

    const int tid = threadIdx.x;
    const int l   = tid & 63;
    const int w   = tid >> 6;            // 0..7
    const int bn  = blockIdx.x;          // 0..63
    const int bz  = blockIdx.y;          // 0..15

    // --- zero Bs (each thread 32 elems, 16B stores) ---
    {
        const u16x8 z8 = {};
        unsigned short* b0 = (unsigned short*)Bs + tid * 32;
        *(u16x8*)(b0)      = z8; *(u16x8*)(b0 + 8)  = z8;
        *(u16x8*)(b0 + 16) = z8; *(u16x8*)(b0 + 24) = z8;
    }
    __syncthreads();

    // --- issue A stage for t=0 (overlaps the sparse gather below) ---
    const int srow8 = l >> 3;
    const int sgq   = (l & 7) ^ srow8;   // pre-swizzled global 16B slot
    const int kbase = bz * KCHUNK;
    #pragma unroll
    for (int io = 0; io < 4; ++io) {
        const int rbase = io * 64 + w * 8;
        gload_lds16(xb + (size_t)(rbase + srow8) * N_IN + kbase + sgq * 8,
                    &As[rbase * BK]);
    }

    // --- sparse gather: 8 threads per B row ---
    {
        const int rl   = tid >> 3;                 // 0..63 local row
        const int sub  = tid & 7;
        const int r    = bn * BN + rl;
        const int base = r * N_IN + kbase;
        const int start = cp[r * CPW + bz];
        const int end   = cp[r * CPW + bz + 1];
        unsigned short* brow = (unsigned short*)Bs + rl * KCHUNK;
        const int rx = (rl & 7) << 3;
        for (int j = start + sub; j < end; j += 8) {
            const int c = idx[j] - base;           // 0..255
            brow[((c & ~7) ^ rx) | (c & 7)] = f2bf(vals[j]);
        }
    }
    __syncthreads();   // Bs ready; As(t=0) ready (barrier drains vmcnt)

    const int wm  = w >> 1;              // 0..3 -> 64 M rows each
    const int wn  = w & 1;               // 0..1 -> 32 N cols each
    const int lr  = l & 15;
    const int lkg = l >> 4;              // 0..3
    f32x4 acc[4][2] = {};

    for (int t = 0; t < KCHUNK / BK; ++t) {        // 4 iterations
        #pragma unroll
        for (int kk = 0; kk < 2; ++kk) {
            const int ksl = kk * 4 + lkg;          // 16B slot within BK
            bf16x8 af[4], bfr[2];
            #pragma unroll
            for (int i = 0; i < 4; ++i) {
                const int m = wm * 64 + i * 16 + lr;
                af[i] = *(const bf16x8*)&As[m * BK + ((ksl ^ (m & 7)) << 3)];
            }
            #pragma unroll
            for (int i = 0; i < 2; ++i) {
                const int n   = wn * 32 + i * 16 + lr;
                const int gsl = t * 8 + ksl;       // slot within KCHUNK
                bfr[i] = *(const bf16x8*)&Bs[n * KCHUNK + ((gsl ^ (n & 7)) << 3)];
            }
            #pragma unroll
            for (int mi = 0; mi < 4; ++mi)
                #pragma unroll
                for (int ni = 0; ni < 2; ++ni)
                    acc[mi][ni] = __builtin_amdgcn_mfma_f32_16x16x32_bf16(
                                      af[mi], bfr[ni], acc[mi][ni], 0, 0, 0);
        }
        __syncthreads();                 // everyone done reading As
        if (t + 1 < KCHUNK / BK) {
            #pragma unroll
            for (int io = 0; io < 4; ++io) {
                const int rbase = io * 64 + w * 8;
                gload_lds16(xb + (size_t)(rbase + srow8) * N_IN + kbase + (t + 1) * BK + sgq * 8,
                            &As[rbase * BK]);
            }
            __syncthreads();             // As(t+1) ready
        }
    }

    // --- epilogue: bf16 partials, C/D layout col=lane&15, row=(l>>4)*4+reg --
    unsigned short* po = part + (size_t)bz * (TOKENS * N_OUT) + (size_t)bn * BN;
    #pragma unroll
    for (int mi = 0; mi < 4; ++mi)
        #pragma unroll
        for (int r = 0; r < 4; ++r) {
            const int m = wm * 64 + mi * 16 + lkg * 4 + r;
            #pragma unroll
            for (int ni = 0; ni < 2; ++ni) {
                const int n = wn * 32 + ni * 16 + lr;
                po[(size_t)m * N_OUT + n] = f2bf(acc[mi][ni][r]);
            }
        }
}

// ---- kernel 4: sum bf16 split-K partials -> f32 out -----------------------
__global__ void reduce_k(const unsigned short* __restrict__ part, float* __restrict__ out) {
    const int i = (blockIdx.x * 256 + threadIdx.x) * 8;
    float a[8] = {};
    for (int z = 0; z < SPLITK; ++z) {
        const u16x8 p = *(const u16x8*)(part + (size_t)z * (TOKENS * N_OUT) + i);
        #pragma unroll
        for (int j = 0; j < 8; ++j) a[j] += bf2f((unsigned short)p[j]);
    }
    float4 o0 = { a[0], a[1], a[2], a[3] };
    float4 o1 = { a[4], a[5], a[6], a[7] };
    *(float4*)(out + i)     = o0;
    *(float4*)(out + i + 4) = o1;
}

// ---- fallback (ws too small): per-output-row CSR, fp32 -------------------
__global__ void fallback_rowcsr(const float* __restrict__ x, const float* __restrict__ vals,
                                const int* __restrict__ idx, float* __restrict__ out) {
    const int o = blockIdx.x;
    const int t = threadIdx.x;
    __shared__ int   scol[256];
    __shared__ float sval[256];

    int lo = 0, hi = N_SPARSE;
    const int target = o * N_IN;
    while (lo < hi) { int m = (lo + hi) >> 1; if (idx[m] < target) lo = m + 1; else hi = m; }
    const int start = lo;
    hi = N_SPARSE;
    const int target2 = target + N_IN;
    while (lo < hi) { int m = (lo + hi) >> 1; if (idx[m] < target2) lo = m + 1; else hi = m; }
    const int end = lo;

    float acc = 0.f;
    const float* xr = x + (size_t)t * N_IN;
    for (int base = start; base < end; base += 256) {
        const int k = base + t;
        if (k < end) { scol[t] = idx[k] - target; sval[t] = vals[k]; }
        __syncthreads();
        const int cnt = min(256, end - base);
        for (int j = 0; j < cnt; ++j) acc += sval[j] * xr[scol[j]];
        __syncthreads();
    }
    out[(size_t)t * N_OUT + o] = acc;
}

extern "C" void kernel_launch(void* const* d_in, const int* in_sizes, int n_in,
                              void* d_out, int out_size, void* d_ws, size_t ws_size,
                              hipStream_t stream) {
    const float* x    = (const float*)d_in[0];
    const float* vals = (const float*)d_in[1];
    const int*   idx  = (const int*)d_in[2];
    float* out = (float*)d_out;

    const size_t part_bytes = (size_t)SPLITK * TOKENS * N_OUT * 2;   // 32 MB
    const size_t xb_bytes   = (size_t)TOKENS * N_IN * 2;             // 2 MB
    const size_t cp_bytes   = (size_t)N_OUT * CPW * 4;               // ~272 KB
    const size_t need = part_bytes + xb_bytes + cp_bytes;            // ~34.3 MB

    if (ws_size >= need) {
        unsigned short* part = (unsigned short*)d_ws;
        unsigned short* xb   = (unsigned short*)((char*)d_ws + part_bytes);
        int*            cp   = (int*)((char*)d_ws + part_bytes + xb_bytes);

        convert_x<<<(TOKENS * N_IN) / 1024, 256, 0, stream>>>(x, xb);
        col_ptr_k<<<(N_OUT * CPW + 255) / 256, 256, 0, stream>>>(idx, cp);
        dim3 grid(N_OUT / BN, SPLITK);
        fused_gemm<<<grid, 512, 0, stream>>>(xb, idx, vals, cp, part);
        reduce_k<<<(TOKENS * N_OUT) / 2048, 256, 0, stream>>>(part, out);
    } else {
        fallback_rowcsr<<<N_OUT, TOKENS, 0, stream>>>(x, vals, idx, out);
    }
}